// Round 1
// baseline (721.185 us; speedup 1.0000x reference)
//
#include <hip/hip_runtime.h>
#include <hip/hip_bf16.h>
#include <stdint.h>

// ---------------------------------------------------------------------------
// FiBiNet forward, MI355X (gfx950).
//   1) se_kernel   : s[b,f] = sigmoid(relu(mean_e(x) @ w1^T) @ w2^T)
//   2) t_kernel    : t1[b,f,:] = x[b,f,:] @ Wb1[f]^T ; t2 = (x*s)[b,f,:] @ Wb2[f]^T
//   3) feat_kernel : feat[b, slot*64+e] (bf16); slot<496: t1[b,i]*x[b,j]
//                                               slot>=496: t2[b,i]*(x[b,j]*s[b,j])
//   4) gemm_bt     : fc0 partials = feat(bf16) @ fc0_w^T   (MFMA 16x16x32, splitK=16)
//   5) reduce      : h1 = relu(sum_z + fc0_b) -> bf16
//   6) gemm_bt     : fc1 partials = h1 @ fc1_w^T           (splitK=16)
//   7) reduce      : h2 = relu(sum_z + fc1_b) -> f32
//   8) fc2_kernel  : y = sigmoid(h2 @ fc2_w^T + fc2_b)
// ---------------------------------------------------------------------------

typedef __attribute__((ext_vector_type(4))) int   int4v;
typedef __attribute__((ext_vector_type(4))) unsigned uint4v;
typedef __attribute__((ext_vector_type(4))) float f32x4;

__device__ __forceinline__ unsigned short f32_bf16(float f) {
  unsigned u = __builtin_bit_cast(unsigned, f);
  u = (u + 0x7fffu + ((u >> 16) & 1u)) >> 16;   // RNE
  return (unsigned short)u;
}
__device__ __forceinline__ unsigned pk_bf16(float lo, float hi) {
  return (unsigned)f32_bf16(lo) | ((unsigned)f32_bf16(hi) << 16);
}

// ------------------------------- SE block ----------------------------------
__global__ __launch_bounds__(256) void se_kernel(
    const float* __restrict__ x, const float* __restrict__ w1,
    const float* __restrict__ w2, float* __restrict__ scale) {
  __shared__ float Z[32];
  __shared__ float A1[4];
  int b = blockIdx.x;
  int t = threadIdx.x;
  int f = t >> 3, sub = t & 7;
  const float4* xp = (const float4*)(x + (size_t)b * 2048 + f * 64 + sub * 8);
  float4 v0 = xp[0], v1 = xp[1];
  float s = v0.x + v0.y + v0.z + v0.w + v1.x + v1.y + v1.z + v1.w;
  s += __shfl_down(s, 4, 8);
  s += __shfl_down(s, 2, 8);
  s += __shfl_down(s, 1, 8);
  if (sub == 0) Z[f] = s * (1.0f / 64.0f);
  __syncthreads();
  if (t < 4) {
    float a = 0.f;
#pragma unroll
    for (int ff = 0; ff < 32; ++ff) a += Z[ff] * w1[t * 32 + ff];
    A1[t] = fmaxf(a, 0.f);
  }
  __syncthreads();
  if (t < 32) {
    float a = 0.f;
#pragma unroll
    for (int r = 0; r < 4; ++r) a += A1[r] * w2[t * 4 + r];
    scale[b * 32 + t] = 1.f / (1.f + expf(-a));
  }
}

// -------------------- per-field bilinear transforms ------------------------
// grid (31, 16, 2) block 256. t[b,f,o] = sum_e in[b,f,e] * W[f,o,e]
__global__ __launch_bounds__(256) void t_kernel(
    const float* __restrict__ x, const float* __restrict__ W1,
    const float* __restrict__ W2, const float* __restrict__ scale,
    float* __restrict__ t1, float* __restrict__ t2) {
  __shared__ float Wl[64 * 65];   // +1 pad breaks stride-64 conflicts
  __shared__ float xs[64 * 65];
  int f = blockIdx.x;
  int b0 = blockIdx.y * 64;
  int which = blockIdx.z;
  const float* W = (which ? W2 : W1) + (size_t)f * 4096;
  float* tout = which ? t2 : t1;
  int t = threadIdx.x;
#pragma unroll
  for (int it = 0; it < 16; ++it) {
    int idx = it * 256 + t;
    int o = idx >> 6, e = idx & 63;
    Wl[o * 65 + e] = W[idx];
  }
#pragma unroll
  for (int it = 0; it < 16; ++it) {
    int idx = it * 256 + t;
    int bl = idx >> 6, e = idx & 63;
    float v = x[(size_t)(b0 + bl) * 2048 + f * 64 + e];
    if (which) v *= scale[(b0 + bl) * 32 + f];
    xs[bl * 65 + e] = v;
  }
  __syncthreads();
  int o = t & 63, g = t >> 6;
  float sum[16];
#pragma unroll
  for (int r = 0; r < 16; ++r) sum[r] = 0.f;
#pragma unroll 4
  for (int e = 0; e < 64; ++e) {
    float wv = Wl[o * 65 + e];
#pragma unroll
    for (int r = 0; r < 16; ++r) sum[r] += xs[(g * 16 + r) * 65 + e] * wv;
  }
#pragma unroll
  for (int r = 0; r < 16; ++r)
    tout[(size_t)(b0 + g * 16 + r) * 1984 + f * 64 + o] = sum[r];
}

// ----------------------- pair feature materialization ----------------------
// one thread = 8 consecutive e of one (b, slot); 16B bf16 store
__global__ __launch_bounds__(256) void feat_kernel(
    const float* __restrict__ x, const float* __restrict__ t1,
    const float* __restrict__ t2, const float* __restrict__ scale,
    unsigned short* __restrict__ feat) {
  int gid = blockIdx.x * 256 + threadIdx.x;
  int b = gid / 7936;                 // 992 slots * 8 chunks
  int rem = gid - b * 7936;
  int s = rem >> 3;
  int e0 = (rem & 7) * 8;
  int which = (s >= 496) ? 1 : 0;
  int p = s - (which ? 496 : 0);
  // decode pair p -> (i, j), lexicographic combinations(32, 2); off(i)=i*(63-i)/2
  int i = (int)((63.0f - sqrtf((float)(3969 - 8 * p))) * 0.5f);
  while ((i * (63 - i)) / 2 > p) --i;
  while (((i + 1) * (62 - i)) / 2 <= p) ++i;
  int j = i + 1 + (p - (i * (63 - i)) / 2);
  const float* tp = (which ? t2 : t1) + (size_t)b * 1984 + i * 64 + e0;
  const float* xp = x + (size_t)b * 2048 + j * 64 + e0;
  float sc = which ? scale[b * 32 + j] : 1.0f;
  float4 ta = *(const float4*)tp, tb = *(const float4*)(tp + 4);
  float4 xa = *(const float4*)xp, xb = *(const float4*)(xp + 4);
  uint4v o;
  o.x = pk_bf16(ta.x * xa.x * sc, ta.y * xa.y * sc);
  o.y = pk_bf16(ta.z * xa.z * sc, ta.w * xa.w * sc);
  o.z = pk_bf16(tb.x * xb.x * sc, tb.y * xb.y * sc);
  o.w = pk_bf16(tb.z * xb.z * sc, tb.w * xb.w * sc);
  *(uint4v*)(feat + (size_t)b * 63488 + s * 64 + e0) = o;
}

// ------------------------------- MFMA GEMM ---------------------------------
// C[m,n] += sum_k A[m,k]*B[n,k]; A bf16 row-major (stride K), B fp32 row-major
// (stride K, converted to bf16 during staging). Partials: Cp[z][M][N].
// 128x128 tile, BK=64, 256 thr (4 waves, 2x2 of 64x64), splitK via blockIdx.z.
#define BM 128
#define BN 128
#define BK 64

__device__ __forceinline__ void mfma_bf16(f32x4& d, int4v a, int4v b) {
  // inline asm avoids builtin-prototype ambiguity (short8 vs bf16x8)
  asm volatile("v_mfma_f32_16x16x32_bf16 %0, %1, %2, %0"
               : "+v"(d) : "v"(a), "v"(b));
}

__global__ __launch_bounds__(256) void gemm_bt(
    const unsigned short* __restrict__ A, const float* __restrict__ B,
    float* __restrict__ Cp, int M, int N, int K, int kz) {
  __shared__ unsigned short sA[BM * BK];   // 16 KB
  __shared__ unsigned short sB[BN * BK];   // 16 KB
  int tid = threadIdx.x;
  int lane = tid & 63, wave = tid >> 6;
  int n0 = blockIdx.x * BN, m0 = blockIdx.y * BM;
  int z = blockIdx.z;
  int wrow = (wave >> 1) * 64, wcol = (wave & 1) * 64;
  int l15 = lane & 15, l4 = lane >> 4;
  f32x4 acc[4][4];
#pragma unroll
  for (int i = 0; i < 4; ++i)
#pragma unroll
    for (int j = 0; j < 4; ++j) acc[i][j] = (f32x4){0.f, 0.f, 0.f, 0.f};

  int kend = z * kz + kz;
  for (int kt = z * kz; kt < kend; kt += BK) {
    // A: async global->LDS, 16B per lane; LDS dest = wave base + lane*16
#pragma unroll
    for (int it = 0; it < 4; ++it) {
      int c = it * 256 + tid;
      int row = c >> 3, col = (c & 7) * 8;
      const unsigned short* gp = A + (size_t)(m0 + row) * K + kt + col;
      __builtin_amdgcn_global_load_lds(
          (const __attribute__((address_space(1))) void*)gp,
          (__attribute__((address_space(3))) void*)(&sA[c * 8]), 16, 0, 0);
    }
    // B: fp32 load + cvt to bf16 + ds_write_b128
#pragma unroll
    for (int it = 0; it < 4; ++it) {
      int c = it * 256 + tid;
      int row = c >> 3, col = (c & 7) * 8;
      const float* gp = B + (size_t)(n0 + row) * K + kt + col;
      float4 f0 = *(const float4*)gp;
      float4 f1 = *(const float4*)(gp + 4);
      uint4v q;
      q.x = pk_bf16(f0.x, f0.y); q.y = pk_bf16(f0.z, f0.w);
      q.z = pk_bf16(f1.x, f1.y); q.w = pk_bf16(f1.z, f1.w);
      *(uint4v*)(&sB[c * 8]) = q;
    }
    __syncthreads();
#pragma unroll
    for (int kk = 0; kk < 2; ++kk) {
      int acol = kk * 32 + l4 * 8;
      int4v av[4], bv[4];
#pragma unroll
      for (int i = 0; i < 4; ++i)
        av[i] = *(const int4v*)&sA[(wrow + i * 16 + l15) * BK + acol];
#pragma unroll
      for (int i = 0; i < 4; ++i)
        bv[i] = *(const int4v*)&sB[(wcol + i * 16 + l15) * BK + acol];
#pragma unroll
      for (int i = 0; i < 4; ++i)
#pragma unroll
        for (int j = 0; j < 4; ++j) mfma_bf16(acc[i][j], av[i], bv[j]);
    }
    __syncthreads();
  }
  // MFMA->VALU/VMEM read-of-D hazard insurance (inline asm hides opcode class)
  asm volatile("s_nop 7\n\ts_nop 7\n\ts_nop 7" ::: "memory");
  float* cp = Cp + (size_t)z * M * N;
#pragma unroll
  for (int i = 0; i < 4; ++i) {
    int rbase = m0 + wrow + i * 16 + l4 * 4;
#pragma unroll
    for (int j = 0; j < 4; ++j) {
      int cc = n0 + wcol + j * 16 + l15;
#pragma unroll
      for (int r = 0; r < 4; ++r)
        cp[(size_t)(rbase + r) * N + cc] = acc[i][j][r];
    }
  }
}

// --------------------- splitK reduce + bias + relu -------------------------
__global__ __launch_bounds__(256) void reduce_bias_act(
    const float* __restrict__ parts, const float* __restrict__ bias,
    int MN, int nmask, int nz, unsigned short* __restrict__ out_bf,
    float* __restrict__ out_f) {
  int idx = blockIdx.x * 256 + threadIdx.x;
  if (idx >= MN) return;
  float s = 0.f;
  for (int z = 0; z < nz; ++z) s += parts[(size_t)z * MN + idx];
  s += bias[idx & nmask];
  s = fmaxf(s, 0.f);
  if (out_bf) out_bf[idx] = f32_bf16(s);
  else out_f[idx] = s;
}

// ------------------------------ fc2 + sigmoid ------------------------------
__global__ __launch_bounds__(256) void fc2_kernel(
    const float* __restrict__ h2, const float* __restrict__ w,
    const float* __restrict__ b, float* __restrict__ out) {
  int wave = threadIdx.x >> 6, lane = threadIdx.x & 63;
  int row = blockIdx.x * 4 + wave;
  const float4* hp = (const float4*)(h2 + (size_t)row * 512);
  const float4* wp = (const float4*)w;
  int i0 = lane * 2;
  float4 a0 = hp[i0], a1 = hp[i0 + 1];
  float4 w0 = wp[i0], w1 = wp[i0 + 1];
  float s = a0.x * w0.x + a0.y * w0.y + a0.z * w0.z + a0.w * w0.w +
            a1.x * w1.x + a1.y * w1.y + a1.z * w1.z + a1.w * w1.w;
#pragma unroll
  for (int off = 32; off > 0; off >>= 1) s += __shfl_down(s, off);
  if (lane == 0) out[row] = 1.f / (1.f + expf(-(s + b[0])));
}

// ---------------------------------------------------------------------------
extern "C" void kernel_launch(void* const* d_in, const int* in_sizes, int n_in,
                              void* d_out, int out_size, void* d_ws, size_t ws_size,
                              hipStream_t stream) {
  const float* x     = (const float*)d_in[0];
  const float* Wb1   = (const float*)d_in[1];
  const float* Wb2   = (const float*)d_in[2];
  const float* se_w1 = (const float*)d_in[3];
  const float* se_w2 = (const float*)d_in[4];
  const float* fc0_w = (const float*)d_in[5];
  const float* fc0_b = (const float*)d_in[6];
  const float* fc1_w = (const float*)d_in[7];
  const float* fc1_b = (const float*)d_in[8];
  const float* fc2_w = (const float*)d_in[9];
  const float* fc2_b = (const float*)d_in[10];
  (void)in_sizes; (void)n_in; (void)out_size; (void)ws_size;

  // workspace layout (all offsets 16B-aligned); total ~208 MB
  char* ws = (char*)d_ws;
  float*          scale = (float*)(ws + 0);               //  128 KB
  float*          t1    = (float*)(ws + 131072);          //  7.75 MB
  float*          t2    = (float*)(ws + 8257536);         //  7.75 MB
  unsigned short* feat  = (unsigned short*)(ws + 16384000);   // 124 MB bf16
  float*          hp    = (float*)(ws + 146407424);       //  64 MB partials (reused fc0/fc1)
  unsigned short* h1b   = (unsigned short*)(ws + 213516288);  // 2 MB bf16
  float*          h2    = (float*)(ws + 215613440);       //  2 MB
  float*          out   = (float*)d_out;

  se_kernel<<<1024, 256, 0, stream>>>(x, se_w1, se_w2, scale);
  t_kernel<<<dim3(31, 16, 2), 256, 0, stream>>>(x, Wb1, Wb2, scale, t1, t2);
  feat_kernel<<<31744, 256, 0, stream>>>(x, t1, t2, scale, feat);
  // fc0: M=1024 N=1024 K=63488, splitK=16 (kz=3968 = 62 k-tiles)
  gemm_bt<<<dim3(8, 8, 16), 256, 0, stream>>>(feat, fc0_w, hp, 1024, 1024, 63488, 3968);
  reduce_bias_act<<<4096, 256, 0, stream>>>(hp, fc0_b, 1024 * 1024, 1023, 16, h1b, nullptr);
  // fc1: M=1024 N=512 K=1024, splitK=16 (kz=64)
  gemm_bt<<<dim3(4, 8, 16), 256, 0, stream>>>(h1b, fc1_w, hp, 1024, 512, 1024, 64);
  reduce_bias_act<<<2048, 256, 0, stream>>>(hp, fc1_b, 1024 * 512, 511, 16, nullptr, h2);
  fc2_kernel<<<256, 256, 0, stream>>>(h2, fc2_w, fc2_b, out);
}

// Round 2
// 582.980 us; speedup vs baseline: 1.2371x; 1.2371x over previous
//
#include <hip/hip_runtime.h>
#include <hip/hip_bf16.h>
#include <stdint.h>

// ---------------------------------------------------------------------------
// FiBiNet forward, MI355X (gfx950).  R2: GEMM xor-swizzled LDS (kill bank
// conflicts) + 256x128 block tile, 128x64 per wave (8x4 of 16x16x32 MFMA).
// ---------------------------------------------------------------------------

typedef __attribute__((ext_vector_type(4))) int   int4v;
typedef __attribute__((ext_vector_type(4))) unsigned uint4v;
typedef __attribute__((ext_vector_type(4))) float f32x4;

__device__ __forceinline__ unsigned short f32_bf16(float f) {
  unsigned u = __builtin_bit_cast(unsigned, f);
  u = (u + 0x7fffu + ((u >> 16) & 1u)) >> 16;   // RNE
  return (unsigned short)u;
}
__device__ __forceinline__ unsigned pk_bf16(float lo, float hi) {
  return (unsigned)f32_bf16(lo) | ((unsigned)f32_bf16(hi) << 16);
}

// ------------------------------- SE block ----------------------------------
__global__ __launch_bounds__(256) void se_kernel(
    const float* __restrict__ x, const float* __restrict__ w1,
    const float* __restrict__ w2, float* __restrict__ scale) {
  __shared__ float Z[32];
  __shared__ float A1[4];
  int b = blockIdx.x;
  int t = threadIdx.x;
  int f = t >> 3, sub = t & 7;
  const float4* xp = (const float4*)(x + (size_t)b * 2048 + f * 64 + sub * 8);
  float4 v0 = xp[0], v1 = xp[1];
  float s = v0.x + v0.y + v0.z + v0.w + v1.x + v1.y + v1.z + v1.w;
  s += __shfl_down(s, 4, 8);
  s += __shfl_down(s, 2, 8);
  s += __shfl_down(s, 1, 8);
  if (sub == 0) Z[f] = s * (1.0f / 64.0f);
  __syncthreads();
  if (t < 4) {
    float a = 0.f;
#pragma unroll
    for (int ff = 0; ff < 32; ++ff) a += Z[ff] * w1[t * 32 + ff];
    A1[t] = fmaxf(a, 0.f);
  }
  __syncthreads();
  if (t < 32) {
    float a = 0.f;
#pragma unroll
    for (int r = 0; r < 4; ++r) a += A1[r] * w2[t * 4 + r];
    scale[b * 32 + t] = 1.f / (1.f + expf(-a));
  }
}

// -------------------- per-field bilinear transforms ------------------------
__global__ __launch_bounds__(256) void t_kernel(
    const float* __restrict__ x, const float* __restrict__ W1,
    const float* __restrict__ W2, const float* __restrict__ scale,
    float* __restrict__ t1, float* __restrict__ t2) {
  __shared__ float Wl[64 * 65];
  __shared__ float xs[64 * 65];
  int f = blockIdx.x;
  int b0 = blockIdx.y * 64;
  int which = blockIdx.z;
  const float* W = (which ? W2 : W1) + (size_t)f * 4096;
  float* tout = which ? t2 : t1;
  int t = threadIdx.x;
#pragma unroll
  for (int it = 0; it < 16; ++it) {
    int idx = it * 256 + t;
    int o = idx >> 6, e = idx & 63;
    Wl[o * 65 + e] = W[idx];
  }
#pragma unroll
  for (int it = 0; it < 16; ++it) {
    int idx = it * 256 + t;
    int bl = idx >> 6, e = idx & 63;
    float v = x[(size_t)(b0 + bl) * 2048 + f * 64 + e];
    if (which) v *= scale[(b0 + bl) * 32 + f];
    xs[bl * 65 + e] = v;
  }
  __syncthreads();
  int o = t & 63, g = t >> 6;
  float sum[16];
#pragma unroll
  for (int r = 0; r < 16; ++r) sum[r] = 0.f;
#pragma unroll 4
  for (int e = 0; e < 64; ++e) {
    float wv = Wl[o * 65 + e];
#pragma unroll
    for (int r = 0; r < 16; ++r) sum[r] += xs[(g * 16 + r) * 65 + e] * wv;
  }
#pragma unroll
  for (int r = 0; r < 16; ++r)
    tout[(size_t)(b0 + g * 16 + r) * 1984 + f * 64 + o] = sum[r];
}

// ----------------------- pair feature materialization ----------------------
__global__ __launch_bounds__(256) void feat_kernel(
    const float* __restrict__ x, const float* __restrict__ t1,
    const float* __restrict__ t2, const float* __restrict__ scale,
    unsigned short* __restrict__ feat) {
  int gid = blockIdx.x * 256 + threadIdx.x;
  int b = gid / 7936;
  int rem = gid - b * 7936;
  int s = rem >> 3;
  int e0 = (rem & 7) * 8;
  int which = (s >= 496) ? 1 : 0;
  int p = s - (which ? 496 : 0);
  int i = (int)((63.0f - sqrtf((float)(3969 - 8 * p))) * 0.5f);
  while ((i * (63 - i)) / 2 > p) --i;
  while (((i + 1) * (62 - i)) / 2 <= p) ++i;
  int j = i + 1 + (p - (i * (63 - i)) / 2);
  const float* tp = (which ? t2 : t1) + (size_t)b * 1984 + i * 64 + e0;
  const float* xp = x + (size_t)b * 2048 + j * 64 + e0;
  float sc = which ? scale[b * 32 + j] : 1.0f;
  float4 ta = *(const float4*)tp, tb = *(const float4*)(tp + 4);
  float4 xa = *(const float4*)xp, xb = *(const float4*)(xp + 4);
  uint4v o;
  o.x = pk_bf16(ta.x * xa.x * sc, ta.y * xa.y * sc);
  o.y = pk_bf16(ta.z * xa.z * sc, ta.w * xa.w * sc);
  o.z = pk_bf16(tb.x * xb.x * sc, tb.y * xb.y * sc);
  o.w = pk_bf16(tb.z * xb.z * sc, tb.w * xb.w * sc);
  *(uint4v*)(feat + (size_t)b * 63488 + s * 64 + e0) = o;
}

// ------------------------------- MFMA GEMM ---------------------------------
// C[m,n] += sum_k A[m,k]*B[n,k]; A bf16 (stride K), B fp32 (stride K, cvt to
// bf16 during staging). 256x128 block tile, BK=64, 4 waves in 2x2, each wave
// 128x64 as 8x4 of 16x16x32.  LDS xor-swizzle: 16B chunk p = l ^ (row&7).
#define BM 256
#define BN 128
#define BK 64

__device__ __forceinline__ void mfma_bf16(f32x4& d, int4v a, int4v b) {
  asm volatile("v_mfma_f32_16x16x32_bf16 %0, %1, %2, %0"
               : "+v"(d) : "v"(a), "v"(b));
}

__global__ __launch_bounds__(256, 2) void gemm_bt(
    const unsigned short* __restrict__ A, const float* __restrict__ B,
    float* __restrict__ Cp, int M, int N, int K, int kz) {
  __shared__ unsigned short sA[BM * BK];   // 32 KB
  __shared__ unsigned short sB[BN * BK];   // 16 KB
  int tid = threadIdx.x;
  int lane = tid & 63, wave = tid >> 6;
  int n0 = blockIdx.x * BN, m0 = blockIdx.y * BM;
  int z = blockIdx.z;
  int wr = (wave >> 1) * 128, wc = (wave & 1) * 64;
  int l15 = lane & 15, l4 = lane >> 4;
  f32x4 acc[8][4];
#pragma unroll
  for (int i = 0; i < 8; ++i)
#pragma unroll
    for (int j = 0; j < 4; ++j) acc[i][j] = (f32x4){0.f, 0.f, 0.f, 0.f};

  int kend = z * kz + kz;
  for (int kt = z * kz; kt < kend; kt += BK) {
    // A: global->LDS DMA. LDS dest is rigid (base+lane*16), so the SWIZZLE is
    // applied to the GLOBAL address: slot c holds logical chunk (c&7)^(r&7).
#pragma unroll
    for (int it = 0; it < 8; ++it) {
      int c = it * 256 + tid;           // 2048 chunks of 16B
      int r = c >> 3, p = c & 7;
      int gcol = (p ^ (r & 7)) * 8;
      const unsigned short* gp = A + (size_t)(m0 + r) * K + kt + gcol;
      __builtin_amdgcn_global_load_lds(
          (const __attribute__((address_space(1))) void*)gp,
          (__attribute__((address_space(3))) void*)(&sA[c * 8]), 16, 0, 0);
    }
    // B: fp32 load + cvt + swizzled ds_write_b128
#pragma unroll
    for (int it = 0; it < 4; ++it) {
      int c = it * 256 + tid;           // 1024 chunks of 16B
      int r = c >> 3, l = c & 7;
      const float* gp = B + (size_t)(n0 + r) * K + kt + l * 8;
      float4 f0 = *(const float4*)gp;
      float4 f1 = *(const float4*)(gp + 4);
      uint4v q;
      q.x = pk_bf16(f0.x, f0.y); q.y = pk_bf16(f0.z, f0.w);
      q.z = pk_bf16(f1.x, f1.y); q.w = pk_bf16(f1.z, f1.w);
      int p = l ^ (r & 7);
      *(uint4v*)(&sB[(r * 8 + p) * 8]) = q;
    }
    __syncthreads();
#pragma unroll
    for (int kk = 0; kk < 2; ++kk) {
      int lc = kk * 4 + l4;             // logical 16B chunk in K
      int4v av[8], bv[4];
#pragma unroll
      for (int i = 0; i < 8; ++i) {
        int ar = wr + i * 16 + l15;
        av[i] = *(const int4v*)&sA[(ar * 8 + (lc ^ (ar & 7))) * 8];
      }
#pragma unroll
      for (int j = 0; j < 4; ++j) {
        int br = wc + j * 16 + l15;
        bv[j] = *(const int4v*)&sB[(br * 8 + (lc ^ (br & 7))) * 8];
      }
#pragma unroll
      for (int i = 0; i < 8; ++i)
#pragma unroll
        for (int j = 0; j < 4; ++j) mfma_bf16(acc[i][j], av[i], bv[j]);
    }
    __syncthreads();
  }
  asm volatile("s_nop 7\n\ts_nop 7\n\ts_nop 7" ::: "memory");
  float* cp = Cp + (size_t)z * M * N;
#pragma unroll
  for (int i = 0; i < 8; ++i) {
    int rbase = m0 + wr + i * 16 + l4 * 4;
#pragma unroll
    for (int j = 0; j < 4; ++j) {
      int cc = n0 + wc + j * 16 + l15;
#pragma unroll
      for (int r = 0; r < 4; ++r)
        cp[(size_t)(rbase + r) * N + cc] = acc[i][j][r];
    }
  }
}

// --------------------- splitK reduce + bias + relu -------------------------
__global__ __launch_bounds__(256) void reduce_bias_act(
    const float* __restrict__ parts, const float* __restrict__ bias,
    int MN, int nmask, int nz, unsigned short* __restrict__ out_bf,
    float* __restrict__ out_f) {
  int idx = blockIdx.x * 256 + threadIdx.x;
  if (idx >= MN) return;
  float s = 0.f;
  for (int z = 0; z < nz; ++z) s += parts[(size_t)z * MN + idx];
  s += bias[idx & nmask];
  s = fmaxf(s, 0.f);
  if (out_bf) out_bf[idx] = f32_bf16(s);
  else out_f[idx] = s;
}

// ------------------------------ fc2 + sigmoid ------------------------------
__global__ __launch_bounds__(256) void fc2_kernel(
    const float* __restrict__ h2, const float* __restrict__ w,
    const float* __restrict__ b, float* __restrict__ out) {
  int wave = threadIdx.x >> 6, lane = threadIdx.x & 63;
  int row = blockIdx.x * 4 + wave;
  const float4* hp = (const float4*)(h2 + (size_t)row * 512);
  const float4* wp = (const float4*)w;
  int i0 = lane * 2;
  float4 a0 = hp[i0], a1 = hp[i0 + 1];
  float4 w0 = wp[i0], w1 = wp[i0 + 1];
  float s = a0.x * w0.x + a0.y * w0.y + a0.z * w0.z + a0.w * w0.w +
            a1.x * w1.x + a1.y * w1.y + a1.z * w1.z + a1.w * w1.w;
#pragma unroll
  for (int off = 32; off > 0; off >>= 1) s += __shfl_down(s, off);
  if (lane == 0) out[row] = 1.f / (1.f + expf(-(s + b[0])));
}

// ---------------------------------------------------------------------------
extern "C" void kernel_launch(void* const* d_in, const int* in_sizes, int n_in,
                              void* d_out, int out_size, void* d_ws, size_t ws_size,
                              hipStream_t stream) {
  const float* x     = (const float*)d_in[0];
  const float* Wb1   = (const float*)d_in[1];
  const float* Wb2   = (const float*)d_in[2];
  const float* se_w1 = (const float*)d_in[3];
  const float* se_w2 = (const float*)d_in[4];
  const float* fc0_w = (const float*)d_in[5];
  const float* fc0_b = (const float*)d_in[6];
  const float* fc1_w = (const float*)d_in[7];
  const float* fc1_b = (const float*)d_in[8];
  const float* fc2_w = (const float*)d_in[9];
  const float* fc2_b = (const float*)d_in[10];
  (void)in_sizes; (void)n_in; (void)out_size; (void)ws_size;

  char* ws = (char*)d_ws;
  float*          scale = (float*)(ws + 0);                   //  128 KB
  float*          t1    = (float*)(ws + 131072);              //  7.75 MB
  float*          t2    = (float*)(ws + 8257536);             //  7.75 MB
  unsigned short* feat  = (unsigned short*)(ws + 16384000);   //  124 MB bf16
  float*          hp    = (float*)(ws + 146407424);           //  64 MB partials
  unsigned short* h1b   = (unsigned short*)(ws + 213516288);  //  2 MB bf16
  float*          h2    = (float*)(ws + 215613440);           //  2 MB
  float*          out   = (float*)d_out;

  se_kernel<<<1024, 256, 0, stream>>>(x, se_w1, se_w2, scale);
  t_kernel<<<dim3(31, 16, 2), 256, 0, stream>>>(x, Wb1, Wb2, scale, t1, t2);
  feat_kernel<<<31744, 256, 0, stream>>>(x, t1, t2, scale, feat);
  // fc0: M=1024 N=1024 K=63488, splitK=16 (kz=3968 = 62 k-tiles)
  gemm_bt<<<dim3(8, 4, 16), 256, 0, stream>>>(feat, fc0_w, hp, 1024, 1024, 63488, 3968);
  reduce_bias_act<<<4096, 256, 0, stream>>>(hp, fc0_b, 1024 * 1024, 1023, 16, h1b, nullptr);
  // fc1: M=1024 N=512 K=1024, splitK=16 (kz=64)
  gemm_bt<<<dim3(4, 4, 16), 256, 0, stream>>>(h1b, fc1_w, hp, 1024, 512, 1024, 64);
  reduce_bias_act<<<2048, 256, 0, stream>>>(hp, fc1_b, 1024 * 512, 511, 16, nullptr, h2);
  fc2_kernel<<<256, 256, 0, stream>>>(h2, fc2_w, fc2_b, out);
}